// Round 18
// baseline (135.031 us; speedup 1.0000x reference)
//
#include <hip/hip_runtime.h>
#include <math.h>

#define NROWS 32768
#define NCODE 1024
#define GAP_THRESH 1.5e-4f  // exact fp32 gap; emulation err ~1e-5, np-ref rounding ~2e-5

typedef __attribute__((ext_vector_type(8))) short bf16x8;   // 8 bf16 = 4 VGPRs
typedef __attribute__((ext_vector_type(4))) float f32x4;    // MFMA acc

__device__ __forceinline__ unsigned short bf16_rne(float f) {
    unsigned u = __float_as_uint(f);
    unsigned r = u + 0x7FFFu + ((u >> 16) & 1u);
    return (unsigned short)(r >> 16);
}

typedef const __attribute__((address_space(1))) unsigned GU;
typedef __attribute__((address_space(3))) unsigned LU;
__device__ __forceinline__ void gl_lds16(const void* g, void* l) {
    __builtin_amdgcn_global_load_lds((GU*)g, (LU*)l, 16, 0, 0);
}
__device__ __forceinline__ void gl_lds4(const void* g, void* l) {
    __builtin_amdgcn_global_load_lds((GU*)g, (LU*)l, 4, 0, 0);
}

// ---------------------------------------------------------------------------
// prep (r14 verbatim): cn4 = ||c||^2+4, minK=+inf bits, ticket=0,
// codebook -> frag-major split-bf16 wsB (chunk cc=64 codes, 16 KB).
// ---------------------------------------------------------------------------
__global__ __launch_bounds__(64) void vq_prep(
    const float* __restrict__ cb, float* __restrict__ cn4,
    unsigned* __restrict__ minK, unsigned* __restrict__ ticket,
    unsigned short* __restrict__ wsB)
{
    int c = blockIdx.x * 64 + threadIdx.x;
    if (c == 0) *ticket = 0u;
    float v[64];
    const float4* src = (const float4*)(cb + (size_t)c * 64);
    float s = 0.f;
    #pragma unroll
    for (int i = 0; i < 16; i++) {
        float4 t = src[i];
        v[i*4+0] = t.x; v[i*4+1] = t.y; v[i*4+2] = t.z; v[i*4+3] = t.w;
        s += t.x*t.x + t.y*t.y + t.z*t.z + t.w*t.w;
    }
    cn4[c] = s + 4.0f;
    minK[c] = 0x7F800000u;   // +inf bits (all dists > 0 -> raw-bit order ok)
    int cc = c >> 6, ct = (c >> 4) & 3, cl = c & 15;
    #pragma unroll
    for (int q = 0; q < 4; q++) {
        int half = q & 1, lo = q >> 1;
        #pragma unroll
        for (int g = 0; g < 4; g++) {
            unsigned short u8[8] __attribute__((aligned(16)));
            #pragma unroll
            for (int j = 0; j < 8; j++) {
                float f = v[half*32 + g*8 + j];
                unsigned short h = bf16_rne(f);
                if (lo) h = bf16_rne(f - __uint_as_float((unsigned)h << 16));
                u8[j] = h;
            }
            size_t off = (size_t)cc * 8192 + ct * 2048 + q * 512 + (g * 16 + cl) * 8;
            *(uint4*)(wsB + off) = *(const uint4*)u8;
        }
    }
}

// ---------------------------------------------------------------------------
// main: 1024 blocks x 512 threads = 64 rows x HALF the codebook (512 codes).
// Code-split doubles blocks without shrinking work-per-barrier: chunk = 64
// codes (Bb 2x16 KB, LDS ~37 KB) -> 4 blocks/CU x 8 waves = 8 waves/SIMD
// (r8-r12 showed 64-row/full-code blocks pin at 4). Wave: g=wi>>1 rowGroup
// (16 rows), h=wi&1 covers ct tiles 2h..2h+1. No epilogue gather here: exact
// per-(row,half) top-2 written coalesced to hD1/hI1/hD2; emb/sumsq/merge in
// tail. Entropy: scrE[512] LDS atomicMin -> filtered global atomicMin(minK).
// ---------------------------------------------------------------------------
__global__ __launch_bounds__(512, 4) void vq_main(
    const float* __restrict__ x, const unsigned short* __restrict__ wsB,
    const float* __restrict__ cn4, unsigned* __restrict__ minK,
    float* __restrict__ hD1, int* __restrict__ hI1, float* __restrict__ hD2)
{
    __shared__ __align__(16) unsigned char Bb[2][16384];
    __shared__ float cn4L[2][64];
    __shared__ unsigned scrE[512];         // per-block per-code min dist (raw bits)
    __shared__ float mD1[128], mD2[128];   // [row 0..63][half 0..1]
    __shared__ int   mI1[128];

    const int tid = threadIdx.x;
    const int lane = tid & 63;
    const int wi = tid >> 6;         // 0..7
    const int g = wi >> 1;           // row group 0..3 (16 rows each)
    const int h = wi & 1;            // tile half: ct = 2h..2h+1
    const int ln15 = lane & 15;
    const int q = lane >> 4;
    const int b = blockIdx.x;
    const int ch = b & 1;            // codebook half: codes ch*512..+512
    const int row0 = (b >> 1) * 64;
    const int rot = (b >> 1) & 7;    // rotate among this half's 8 chunks

    scrE[tid] = 0x7F800000u;         // 512 entries, 512 threads

    // preload chunk 'rot' (B 16KB + cn4 64) straight into LDS
    const char* wsBb = (const char*)wsB;
    {
        int wbase = (tid & ~63) * 16;   // wave-uniform LDS base
        #pragma unroll
        for (int i = 0; i < 2; i++)
            gl_lds16(wsBb + (size_t)(ch*8 + rot)*16384 + (i*512 + tid)*16,
                     (void*)&Bb[0][i*8192 + wbase]);
        if (wi == 0) gl_lds4(cn4 + (ch*8 + rot)*64 + lane, (void*)&cn4L[0][0]);
    }

    // ---- A: 16 rows fp32 -> split-bf16 frags in regs; row norms via shfl ----
    bf16x8 Ah0, Ah1, Al0, Al1;
    float xnm4[4];
    {
        const float* xr = x + (size_t)(row0 + g*16 + ln15) * 64 + q * 8;
        float4 f0 = *(const float4*)xr;
        float4 f1 = *(const float4*)(xr + 4);
        float4 f2 = *(const float4*)(xr + 32);
        float4 f3 = *(const float4*)(xr + 36);
        float fa[8] = {f0.x,f0.y,f0.z,f0.w,f1.x,f1.y,f1.z,f1.w};
        float fb[8] = {f2.x,f2.y,f2.z,f2.w,f3.x,f3.y,f3.z,f3.w};
        unsigned short hh8[8] __attribute__((aligned(16)));
        unsigned short ll8[8] __attribute__((aligned(16)));
        unsigned short h28[8] __attribute__((aligned(16)));
        unsigned short l28[8] __attribute__((aligned(16)));
        float ss = 0.f;
        #pragma unroll
        for (int j = 0; j < 8; j++) {
            ss += fa[j]*fa[j] + fb[j]*fb[j];
            unsigned short hh = bf16_rne(fa[j]);
            hh8[j] = hh; ll8[j] = bf16_rne(fa[j] - __uint_as_float((unsigned)hh << 16));
            hh = bf16_rne(fb[j]);
            h28[j] = hh; l28[j] = bf16_rne(fb[j] - __uint_as_float((unsigned)hh << 16));
        }
        Ah0 = *(const bf16x8*)hh8; Al0 = *(const bf16x8*)ll8;
        Ah1 = *(const bf16x8*)h28; Al1 = *(const bf16x8*)l28;
        ss += __shfl_xor(ss, 16);
        ss += __shfl_xor(ss, 32);            // ||x_row(ln15)||^2
        #pragma unroll
        for (int r = 0; r < 4; r++)
            xnm4[r] = __shfl(ss, (q << 2) | r, 64) - 4.0f;  // xn(row q*4+r) - 4
    }

    float d1[4], d2[4];
    int   i1[4];
    #pragma unroll
    for (int r = 0; r < 4; r++) { d1[r] = INFINITY; d2[r] = INFINITY; i1[r] = 0; }

    // ---- chunk loop: 8 chunks x 64 codes (rotated order) ----
    for (int s = 0; s < 8; s++) {
        __syncthreads();   // Bb[s&1]+cn4L[s&1] staged; Bb[nb] free
        const int cb_ = s & 1, nb = (s + 1) & 1;
        const int cphys = (s + rot) & 7;
        if (s < 7) {
            const int cnx = (s + 1 + rot) & 7;
            int wbase = (tid & ~63) * 16;
            #pragma unroll
            for (int i = 0; i < 2; i++)
                gl_lds16(wsBb + (size_t)(ch*8 + cnx)*16384 + (i*512 + tid)*16,
                         (void*)&Bb[nb][i*8192 + wbase]);
            if (wi == 0) gl_lds4(cn4 + (ch*8 + cnx)*64 + lane, (void*)&cn4L[nb][0]);
        }
        const unsigned char* buf = Bb[cb_];
        #pragma unroll
        for (int lct = 0; lct < 2; lct++) {
            const int ct = 2*h + lct;                       // 0..3 within 64-code chunk
            const unsigned char* tb = buf + ct*4096;
            bf16x8 Bh0 = *(const bf16x8*)(tb +    0 + lane*16);
            bf16x8 Bh1 = *(const bf16x8*)(tb + 1024 + lane*16);
            bf16x8 Bl0 = *(const bf16x8*)(tb + 2048 + lane*16);
            bf16x8 Bl1 = *(const bf16x8*)(tb + 3072 + lane*16);
            float cn4v = cn4L[cb_][ct*16 + ln15];
            int kloc = cphys*64 + ct*16 + ln15;             // 0..511 within half
            int kid  = ch*512 + kloc;                       // global code id
            f32x4 z = {0.f, 0.f, 0.f, 0.f};
            f32x4 acc0 = __builtin_amdgcn_mfma_f32_16x16x32_bf16(Ah0, Bh0, z, 0, 0, 0);
            f32x4 acc1 = __builtin_amdgcn_mfma_f32_16x16x32_bf16(Ah1, Bh1, z, 0, 0, 0);
            acc0 = __builtin_amdgcn_mfma_f32_16x16x32_bf16(Ah0, Bl0, acc0, 0, 0, 0);
            acc1 = __builtin_amdgcn_mfma_f32_16x16x32_bf16(Ah1, Bl1, acc1, 0, 0, 0);
            acc0 = __builtin_amdgcn_mfma_f32_16x16x32_bf16(Al0, Bh0, acc0, 0, 0, 0);
            acc1 = __builtin_amdgcn_mfma_f32_16x16x32_bf16(Al1, Bh1, acc1, 0, 0, 0);
            float cminv = INFINITY;
            #pragma unroll
            for (int r = 0; r < 4; r++) {
                float sdot = acc0[r] + acc1[r];
                float wv = fmaf(sdot, -2.0f, cn4v);   // 4 + cn - 2s  (>0)
                bool lt = wv < d1[r];
                d2[r] = lt ? d1[r] : fminf(d2[r], wv);
                i1[r] = lt ? kid   : i1[r];
                d1[r] = lt ? wv    : d1[r];
                cminv = fminf(cminv, wv + xnm4[r]);   // full dist (entropy)
            }
            cminv = fminf(cminv, __shfl_xor(cminv, 16));
            cminv = fminf(cminv, __shfl_xor(cminv, 32));   // min over wave's 16 rows
            if (q == lct) atomicMin(&scrE[kloc], __float_as_uint(cminv));
        }
    }
    __syncthreads();   // scrE complete; all compute done

    // ---- butterfly exact top-2 merge across the 16 code-column lanes ----
    #pragma unroll
    for (int d = 1; d < 16; d <<= 1) {
        #pragma unroll
        for (int r = 0; r < 4; r++) {
            float od1 = __shfl_xor(d1[r], d);
            int   oi1 = __shfl_xor(i1[r], d);
            float od2 = __shfl_xor(d2[r], d);
            bool take = (od1 < d1[r]) || (od1 == d1[r] && oi1 < i1[r]);
            float loser = take ? d1[r] : od1;
            d2[r] = fminf(fminf(d2[r], od2), loser);
            d1[r] = take ? od1 : d1[r];
            i1[r] = take ? oi1 : i1[r];
        }
    }
    if (ln15 == 0) {
        #pragma unroll
        for (int r = 0; r < 4; r++) {
            int idx = (g*16 + q*4 + r) * 2 + h;
            mD1[idx] = d1[r]; mI1[idx] = i1[r]; mD2[idx] = d2[r];
        }
    }
    __syncthreads();   // per-tile-half candidates staged

    // ---- cross-tile-half merge -> per-(row, codebook-half) record ----
    if (tid < 64) {
        float a1 = mD1[tid*2],   b1 = mD1[tid*2+1];
        int   ai = mI1[tid*2],   bi = mI1[tid*2+1];
        float a2 = mD2[tid*2],   b2 = mD2[tid*2+1];
        bool ta = (a1 < b1) || (a1 == b1 && ai < bi);
        size_t o = (size_t)ch*NROWS + row0 + tid;
        hD1[o] = ta ? a1 : b1;
        hI1[o] = ta ? ai : bi;
        hD2[o] = ta ? fminf(a2, b1) : fminf(b2, a1);
    }

    // ---- entropy: filtered global atomicMin (prep inited minK) ----
    {
        unsigned u0 = scrE[tid];
        if (u0 < minK[ch*512 + tid]) atomicMin(&minK[ch*512 + tid], u0);
    }
}

// ---------------------------------------------------------------------------
// tail: 256 blocks x 256 threads, 128 rows/block.
// (A) merge the 2 codebook-half records -> token + gap -> fixup list.
// (B) emb gather + sumsq (coalesced) -> sumsqP.
// (C) fp64 fixup, cb LDS-staged (r14-proven) -> deltaP.
// (D) last-ticket block: loss from minK + sumsqP + deltaP.
// ---------------------------------------------------------------------------
__global__ __launch_bounds__(256) void vq_tail(
    const float* __restrict__ x, const float* __restrict__ cb,
    float* __restrict__ out, const float* __restrict__ hD1,
    const int* __restrict__ hI1, const float* __restrict__ hD2,
    const unsigned* __restrict__ minK, float* __restrict__ sumsqP,
    float* __restrict__ deltaP, unsigned* __restrict__ ticket,
    float* __restrict__ out_loss)
{
    __shared__ __align__(16) float cbS[16384];   // 64 KB: 256 codes x 64 dims
    __shared__ double xs[64];
    __shared__ double bd[256];
    __shared__ int    bix[256];
    __shared__ int    tokS[128];
    __shared__ int    listRow[32], listTok[32];
    __shared__ int    lcnt;
    __shared__ double deltaS;
    __shared__ unsigned lastS;
    __shared__ float redS[4], redS2[4];

    const int tid = threadIdx.x;
    const int lane = tid & 63;
    const int w = tid >> 6;
    const int b = blockIdx.x;
    const int rb0 = b * 128;

    if (tid == 0) { lcnt = 0; deltaS = 0.0; }
    __syncthreads();

    // ---- A: merge halves -> token, gap check (coalesced reads) ----
    if (tid < 128) {
        int row = rb0 + tid;
        float a1 = hD1[row],         b1 = hD1[NROWS + row];
        int   ai = hI1[row],         bi = hI1[NROWS + row];
        float a2 = hD2[row],         b2 = hD2[NROWS + row];
        bool ta = (a1 < b1) || (a1 == b1 && ai < bi);
        float D1 = ta ? a1 : b1;
        int   I1 = ta ? ai : bi;
        float D2 = ta ? fminf(a2, b1) : fminf(b2, a1);
        tokS[tid] = I1;
        if (D2 - D1 < GAP_THRESH) {
            int idx = atomicAdd(&lcnt, 1);
            if (idx < 32) { listRow[idx] = row; listTok[idx] = I1; }
        }
    }
    __syncthreads();

    // ---- B: emb gather + sumsq (128 rows x 16 float4; 8 units/thread) ----
    {
        float acc2 = 0.f;
        #pragma unroll
        for (int j = 0; j < 8; j++) {
            int u = j*256 + tid;
            int row = u >> 4, c4 = u & 15;
            int tok = tokS[row];
            float4 c = ((const float4*)(cb + (size_t)tok*64))[c4];
            float4 xx = ((const float4*)(x + (size_t)(rb0 + row)*64))[c4];
            ((float4*)(out + (size_t)(rb0 + row)*64))[c4] = c;
            float dx = c.x-xx.x, dy = c.y-xx.y, dz = c.z-xx.z, dw = c.w-xx.w;
            acc2 += dx*dx + dy*dy + dz*dz + dw*dw;
        }
        #pragma unroll
        for (int o = 32; o > 0; o >>= 1) acc2 += __shfl_down(acc2, o);
        if (lane == 0) redS[w] = acc2;
        __syncthreads();
        if (tid == 0) sumsqP[b] = redS[0] + redS[1] + redS[2] + redS[3];
    }

    // ---- C: fp64 fixup, cb staged through LDS (coalesced) ----
    int nfix = lcnt < 32 ? lcnt : 32;
    for (int i = 0; i < nfix; i++) {
        int row = listRow[i], oldk = listTok[i];
        __syncthreads();
        if (tid < 64) xs[tid] = (double)x[(size_t)row*64 + tid];
        __syncthreads();
        double xn = 0.0;
        #pragma unroll 8
        for (int d = 0; d < 64; d++) xn += xs[d]*xs[d];
        double best = INFINITY; int bk = 1 << 30;
        for (int bb = 0; bb < 4; bb++) {        // 256 codes per batch
            __syncthreads();                    // cbS free for reuse
            #pragma unroll
            for (int k = 0; k < 16; k++)        // 64 KB coalesced: 16 float4/thread
                ((float4*)cbS)[k*256 + tid] = ((const float4*)cb)[bb*4096 + k*256 + tid];
            __syncthreads();
            int kcode = bb*256 + tid;
            const int t6 = tid & 63;
            double dot = 0.0, cn2 = 0.0;
            #pragma unroll 8
            for (int dd = 0; dd < 64; dd++) {
                int d = (dd + t6) & 63;         // rotation: 2 lanes/bank (free)
                double cv = (double)cbS[tid*64 + d];
                dot = fma(xs[d], cv, dot);
                cn2 = fma(cv, cv, cn2);
            }
            double dist = (xn - 2.0*dot) + cn2;
            if (dist < best || (dist == best && kcode < bk)) { best = dist; bk = kcode; }
        }
        bd[tid] = best; bix[tid] = bk;
        __syncthreads();
        for (int s = 128; s > 0; s >>= 1) {
            if (tid < s) {
                double od = bd[tid+s]; int ok = bix[tid+s];
                if (od < bd[tid] || (od == bd[tid] && ok < bix[tid])) { bd[tid] = od; bix[tid] = ok; }
            }
            __syncthreads();
        }
        int bestk = bix[0];
        if (bestk != oldk) {
            double part = 0.0;
            if (tid < 64) {
                float cn = cb[(size_t)bestk*64 + tid];
                float co = cb[(size_t)oldk*64 + tid];
                out[(size_t)row*64 + tid] = cn;
                double dn = (double)cn - xs[tid];
                double dl = (double)co - xs[tid];
                part = dn*dn - dl*dl;
            }
            __syncthreads();
            bd[tid] = part;
            __syncthreads();
            for (int s = 128; s > 0; s >>= 1) {
                if (tid < s) bd[tid] += bd[tid+s];
                __syncthreads();
            }
            if (tid == 0) deltaS += bd[0];
        }
    }
    __syncthreads();
    if (tid == 0) deltaP[b] = (float)deltaS;   // always written

    // ---- D: last block assembles the loss ----
    __syncthreads();
    if (tid == 0) {
        __threadfence();
        lastS = (atomicAdd(ticket, 1u) == 255u) ? 1u : 0u;
    }
    __syncthreads();
    if (lastS) {
        __threadfence();
        volatile const float* sp = sumsqP;
        volatile const float* dp = deltaP;
        float sq = sp[tid] + dp[tid];
        float es = 0.f;
        #pragma unroll
        for (int jj = 0; jj < 4; jj++)
            es += __uint_as_float(minK[jj*256 + tid]);   // raw bits of positive dists
        #pragma unroll
        for (int o = 32; o > 0; o >>= 1) { sq += __shfl_down(sq, o); es += __shfl_down(es, o); }
        if (lane == 0) { redS[w] = sq; redS2[w] = es; }
        __syncthreads();
        if (tid == 0) {
            float S = redS[0] + redS[1] + redS[2] + redS[3];
            float E = redS2[0] + redS2[1] + redS2[2] + redS2[3];
            out_loss[0] = 1.25f * (S / 2097152.0f) + 0.1f * (E / 1024.0f);
        }
    }
}

extern "C" void kernel_launch(void* const* d_in, const int* in_sizes, int n_in,
                              void* d_out, int out_size, void* d_ws, size_t ws_size,
                              hipStream_t stream) {
    const float* x  = (const float*)d_in[0];   // [32768, 64]
    const float* cb = (const float*)d_in[1];   // [1024, 64]
    float* out = (float*)d_out;                // [0,2097152): emb; [2097152]: loss

    char* ws = (char*)d_ws;
    unsigned*       ticket = (unsigned*)ws;                 // @0
    unsigned*       minK   = (unsigned*)(ws + 1024);        // 4 KB [1024] raw-bit dist
    float*          sumsqP = (float*)(ws + 8192);           // 1 KB [256]
    float*          deltaP = (float*)(ws + 12288);          // 1 KB [256]
    float*          cn4    = (float*)(ws + 16384);          // 4 KB
    float*          hD1    = (float*)(ws + 32768);          // 256 KB [2][32768]
    int*            hI1    = (int*)(ws + 294912);           // 256 KB
    float*          hD2    = (float*)(ws + 557056);         // 256 KB
    unsigned short* wsB    = (unsigned short*)(ws + 819200);// 256 KB frag-major

    vq_prep<<<16,   64,  0, stream>>>(cb, cn4, minK, ticket, wsB);
    vq_main<<<1024, 512, 0, stream>>>(x, wsB, cn4, minK, hD1, hI1, hD2);
    vq_tail<<<256,  256, 0, stream>>>(x, cb, out, hD1, hI1, hD2, minK, sumsqP,
                                      deltaP, ticket, out + 2097152);
}

// Round 19
// 115.021 us; speedup vs baseline: 1.1740x; 1.1740x over previous
//
#include <hip/hip_runtime.h>
#include <math.h>

#define NROWS 32768
#define NCODE 1024
#define AMB_CAP 8192
#define GAP_THRESH 1.5e-4f  // exact fp32 gap; emulation err ~1e-5, np-ref rounding ~2e-5

typedef __attribute__((ext_vector_type(8))) short bf16x8;   // 8 bf16 = 4 VGPRs
typedef __attribute__((ext_vector_type(4))) float f32x4;    // MFMA acc

__device__ __forceinline__ unsigned short bf16_rne(float f) {
    unsigned u = __float_as_uint(f);
    unsigned r = u + 0x7FFFu + ((u >> 16) & 1u);
    return (unsigned short)(r >> 16);
}

typedef const __attribute__((address_space(1))) unsigned GU;
typedef __attribute__((address_space(3))) unsigned LU;
__device__ __forceinline__ void gl_lds16(const void* g, void* l) {
    __builtin_amdgcn_global_load_lds((GU*)g, (LU*)l, 16, 0, 0);
}
__device__ __forceinline__ void gl_lds4(const void* g, void* l) {
    __builtin_amdgcn_global_load_lds((GU*)g, (LU*)l, 4, 0, 0);
}

// ---------------------------------------------------------------------------
// prep: cn4 = ||c||^2+4, minK=+inf bits, zero counter/gsumsq/ticket,
// codebook -> frag-major split-bf16 (wsB). 16 blocks x 64 codes. (r12 verbatim)
// ---------------------------------------------------------------------------
__global__ __launch_bounds__(64) void vq_prep(
    const float* __restrict__ cb, float* __restrict__ cn4,
    unsigned* __restrict__ minK, unsigned* __restrict__ counter,
    float* __restrict__ gsumsq, unsigned* __restrict__ ticket,
    unsigned short* __restrict__ wsB)
{
    int c = blockIdx.x * 64 + threadIdx.x;
    if (c == 0) { *counter = 0u; *gsumsq = 0.f; *ticket = 0u; }
    float v[64];
    const float4* src = (const float4*)(cb + (size_t)c * 64);
    float s = 0.f;
    #pragma unroll
    for (int i = 0; i < 16; i++) {
        float4 t = src[i];
        v[i*4+0] = t.x; v[i*4+1] = t.y; v[i*4+2] = t.z; v[i*4+3] = t.w;
        s += t.x*t.x + t.y*t.y + t.z*t.z + t.w*t.w;
    }
    cn4[c] = s + 4.0f;
    minK[c] = 0x7F800000u;   // +inf bits (all dists > 0 -> raw-bit order ok)
    int cc = c >> 6, ct = (c >> 4) & 3, cl = c & 15;
    #pragma unroll
    for (int q = 0; q < 4; q++) {
        int half = q & 1, lo = q >> 1;
        #pragma unroll
        for (int g = 0; g < 4; g++) {
            unsigned short u8[8] __attribute__((aligned(16)));
            #pragma unroll
            for (int j = 0; j < 8; j++) {
                float f = v[half*32 + g*8 + j];
                unsigned short h = bf16_rne(f);
                if (lo) h = bf16_rne(f - __uint_as_float((unsigned)h << 16));
                u8[j] = h;
            }
            size_t off = (size_t)cc * 8192 + ct * 2048 + q * 512 + (g * 16 + cl) * 8;
            *(uint4*)(wsB + off) = *(const uint4*)u8;
        }
    }
}

// ---------------------------------------------------------------------------
// main: 512 blocks x 512 threads = 64 rows x ALL 1024 codes; 8 chunks of 128
// codes double-buffered via global_load_lds(16B). (r12/r14 verbatim — the
// empirical optimum across rounds 9-18's ten structural variants)
// ---------------------------------------------------------------------------
__global__ __launch_bounds__(512, 4) void vq_main(
    const float* __restrict__ x, const float* __restrict__ cb,
    const unsigned short* __restrict__ wsB, const float* __restrict__ cn4,
    float* __restrict__ out, unsigned* __restrict__ minK,
    unsigned* __restrict__ counter, int* __restrict__ amb,
    float* __restrict__ gsumsq)
{
    __shared__ __align__(16) unsigned char Bb[2][32768];
    __shared__ float cn4L[2][128];
    __shared__ unsigned scrE[1024];        // per-block per-code min dist (raw bits)
    __shared__ float mD1[128], mD2[128];   // [row 0..63][half 0..1]
    __shared__ int   mI1[128];
    __shared__ int   tokS[64];
    __shared__ float redS[8];

    const int tid = threadIdx.x;
    const int lane = tid & 63;
    const int wi = tid >> 6;         // 0..7
    const int g = wi >> 1;           // row group 0..3 (16 rows each)
    const int h = wi & 1;            // code half: ct tiles 4h..4h+3
    const int ln15 = lane & 15;
    const int q = lane >> 4;
    const int row0 = blockIdx.x * 64;
    const int rot = blockIdx.x & 7;  // 8 chunks of 128 codes

    // init scrE to +inf bits
    scrE[tid] = 0x7F800000u;
    scrE[512 + tid] = 0x7F800000u;

    // preload physical chunk 'rot' (B 32KB + cn4 128) straight into LDS
    const char* wsBb = (const char*)wsB;
    {
        int wbase = (tid & ~63) * 16;   // wave-uniform LDS base
        #pragma unroll
        for (int i = 0; i < 4; i++)
            gl_lds16(wsBb + (size_t)rot*32768 + (i*512 + tid)*16,
                     (void*)&Bb[0][i*8192 + wbase]);
        if (wi == 0) {
            gl_lds4(cn4 + rot*128 + lane,      (void*)&cn4L[0][0]);
            gl_lds4(cn4 + rot*128 + 64 + lane, (void*)&cn4L[0][64]);
        }
    }

    // ---- A: 16 rows fp32 -> split-bf16 frags in regs; row norms via shfl ----
    bf16x8 Ah0, Ah1, Al0, Al1;
    float xnm4[4];
    {
        const float* xr = x + (size_t)(row0 + g*16 + ln15) * 64 + q * 8;
        float4 f0 = *(const float4*)xr;
        float4 f1 = *(const float4*)(xr + 4);
        float4 f2 = *(const float4*)(xr + 32);
        float4 f3 = *(const float4*)(xr + 36);
        float fa[8] = {f0.x,f0.y,f0.z,f0.w,f1.x,f1.y,f1.z,f1.w};
        float fb[8] = {f2.x,f2.y,f2.z,f2.w,f3.x,f3.y,f3.z,f3.w};
        unsigned short hh8[8] __attribute__((aligned(16)));
        unsigned short ll8[8] __attribute__((aligned(16)));
        unsigned short h28[8] __attribute__((aligned(16)));
        unsigned short l28[8] __attribute__((aligned(16)));
        float ss = 0.f;
        #pragma unroll
        for (int j = 0; j < 8; j++) {
            ss += fa[j]*fa[j] + fb[j]*fb[j];
            unsigned short hh = bf16_rne(fa[j]);
            hh8[j] = hh; ll8[j] = bf16_rne(fa[j] - __uint_as_float((unsigned)hh << 16));
            hh = bf16_rne(fb[j]);
            h28[j] = hh; l28[j] = bf16_rne(fb[j] - __uint_as_float((unsigned)hh << 16));
        }
        Ah0 = *(const bf16x8*)hh8; Al0 = *(const bf16x8*)ll8;
        Ah1 = *(const bf16x8*)h28; Al1 = *(const bf16x8*)l28;
        ss += __shfl_xor(ss, 16);
        ss += __shfl_xor(ss, 32);            // ||x_row(ln15)||^2
        #pragma unroll
        for (int r = 0; r < 4; r++)
            xnm4[r] = __shfl(ss, (q << 2) | r, 64) - 4.0f;  // xn(row q*4+r) - 4
    }

    float d1[4], d2[4];
    int   i1[4];
    #pragma unroll
    for (int r = 0; r < 4; r++) { d1[r] = INFINITY; d2[r] = INFINITY; i1[r] = 0; }

    // ---- chunk loop: 8 chunks x 128 codes (rotated order) ----
    for (int s = 0; s < 8; s++) {
        __syncthreads();   // drains prefetch: buf[s&1]+cn4L[s&1] ready; buf[nb] free
        const int cb_ = s & 1, nb = (s + 1) & 1;
        const int cphys = (s + rot) & 7;
        if (s < 7) {
            const int cnx = (s + 1 + rot) & 7;
            int wbase = (tid & ~63) * 16;
            #pragma unroll
            for (int i = 0; i < 4; i++)
                gl_lds16(wsBb + (size_t)cnx*32768 + (i*512 + tid)*16,
                         (void*)&Bb[nb][i*8192 + wbase]);
            if (wi == 0) {
                gl_lds4(cn4 + cnx*128 + lane,      (void*)&cn4L[nb][0]);
                gl_lds4(cn4 + cnx*128 + 64 + lane, (void*)&cn4L[nb][64]);
            }
        }
        const unsigned char* buf = Bb[cb_];
        #pragma unroll
        for (int lct = 0; lct < 4; lct++) {
            const int ct = 4*h + lct;                       // 0..7 within 128-code chunk
            const unsigned char* tb = buf + (ct >> 2)*16384 + (ct & 3)*4096;
            bf16x8 Bh0 = *(const bf16x8*)(tb +    0 + lane*16);
            bf16x8 Bh1 = *(const bf16x8*)(tb + 1024 + lane*16);
            bf16x8 Bl0 = *(const bf16x8*)(tb + 2048 + lane*16);
            bf16x8 Bl1 = *(const bf16x8*)(tb + 3072 + lane*16);
            float cn4v = cn4L[cb_][ct*16 + ln15];
            int kid = cphys*128 + ct*16 + ln15;
            f32x4 z = {0.f, 0.f, 0.f, 0.f};
            f32x4 acc0 = __builtin_amdgcn_mfma_f32_16x16x32_bf16(Ah0, Bh0, z, 0, 0, 0);
            f32x4 acc1 = __builtin_amdgcn_mfma_f32_16x16x32_bf16(Ah1, Bh1, z, 0, 0, 0);
            acc0 = __builtin_amdgcn_mfma_f32_16x16x32_bf16(Ah0, Bl0, acc0, 0, 0, 0);
            acc1 = __builtin_amdgcn_mfma_f32_16x16x32_bf16(Ah1, Bl1, acc1, 0, 0, 0);
            acc0 = __builtin_amdgcn_mfma_f32_16x16x32_bf16(Al0, Bh0, acc0, 0, 0, 0);
            acc1 = __builtin_amdgcn_mfma_f32_16x16x32_bf16(Al1, Bh1, acc1, 0, 0, 0);
            float cminv = INFINITY;
            #pragma unroll
            for (int r = 0; r < 4; r++) {
                float sdot = acc0[r] + acc1[r];
                float wv = fmaf(sdot, -2.0f, cn4v);   // 4 + cn - 2s  (>0)
                bool lt = wv < d1[r];
                d2[r] = lt ? d1[r] : fminf(d2[r], wv);
                i1[r] = lt ? kid   : i1[r];
                d1[r] = lt ? wv    : d1[r];
                cminv = fminf(cminv, wv + xnm4[r]);   // full dist (entropy)
            }
            cminv = fminf(cminv, __shfl_xor(cminv, 16));
            cminv = fminf(cminv, __shfl_xor(cminv, 32));   // min over wave's 16 rows
            if (q == lct) atomicMin(&scrE[kid], __float_as_uint(cminv));
        }
    }
    __syncthreads();   // scrE complete; all compute done

    // ---- butterfly exact top-2 merge across the 16 code-column lanes ----
    #pragma unroll
    for (int d = 1; d < 16; d <<= 1) {
        #pragma unroll
        for (int r = 0; r < 4; r++) {
            float od1 = __shfl_xor(d1[r], d);
            int   oi1 = __shfl_xor(i1[r], d);
            float od2 = __shfl_xor(d2[r], d);
            bool take = (od1 < d1[r]) || (od1 == d1[r] && oi1 < i1[r]);
            float loser = take ? d1[r] : od1;
            d2[r] = fminf(fminf(d2[r], od2), loser);
            d1[r] = take ? od1 : d1[r];
            i1[r] = take ? oi1 : i1[r];
        }
    }
    if (ln15 == 0) {
        #pragma unroll
        for (int r = 0; r < 4; r++) {
            int idx = (g*16 + q*4 + r) * 2 + h;
            mD1[idx] = d1[r]; mI1[idx] = i1[r]; mD2[idx] = d2[r];
        }
    }
    __syncthreads();   // per-half candidates staged

    // ---- exact cross-half merge -> token + ambiguity (1 thread/row) ----
    if (tid < 64) {
        float a1 = mD1[tid*2],   b1 = mD1[tid*2+1];
        int   ai = mI1[tid*2],   bi = mI1[tid*2+1];
        float a2 = mD2[tid*2],   b2 = mD2[tid*2+1];
        bool ta = (a1 < b1) || (a1 == b1 && ai < bi);
        float D1 = ta ? a1 : b1;
        int   I1 = ta ? ai : bi;
        float D2 = ta ? fminf(a2, b1) : fminf(b2, a1);
        tokS[tid] = I1;
        if (D2 - D1 < GAP_THRESH) {
            unsigned idx = atomicAdd(counter, 1u);
            if (idx < AMB_CAP) { amb[2*idx] = row0 + tid; amb[2*idx+1] = I1; }
        }
    }

    // ---- entropy: filtered global atomicMin ----
    {
        unsigned u0 = scrE[tid];
        if (u0 < minK[tid]) atomicMin(&minK[tid], u0);          // race benign: monotone
        unsigned u1 = scrE[512 + tid];
        if (u1 < minK[512 + tid]) atomicMin(&minK[512 + tid], u1);
    }
    __syncthreads();   // tokS ready

    // ---- emb gather + sumsq (512 threads x 2 float4 = 64 rows x 16) ----
    {
        float acc2 = 0.f;
        #pragma unroll
        for (int uu = 0; uu < 2; uu++) {
            int u = uu*512 + tid;
            int row = u >> 4, c4 = u & 15;
            int tok = tokS[row];
            float4 c = ((const float4*)(cb + (size_t)tok*64))[c4];
            float4 xx = ((const float4*)(x + (size_t)(row0 + row)*64))[c4];
            ((float4*)(out + (size_t)(row0 + row)*64))[c4] = c;
            float dx = c.x-xx.x, dy = c.y-xx.y, dz = c.z-xx.z, dw = c.w-xx.w;
            acc2 += dx*dx + dy*dy + dz*dz + dw*dw;
        }
        #pragma unroll
        for (int o = 32; o > 0; o >>= 1) acc2 += __shfl_down(acc2, o);
        if (lane == 0) redS[wi] = acc2;
        __syncthreads();
        if (tid == 0) {
            float t = 0.f;
            #pragma unroll
            for (int w = 0; w < 8; w++) t += redS[w];
            atomicAdd(gsumsq, t);
        }
    }
}

// ---------------------------------------------------------------------------
// tail: 64 blocks. (A) fp64 fixup with cb staged through LDS in 4 coalesced
// 64-KB batches (r14's win: removed the ~50 us uncoalesced-read floor).
// (B) last-ticket block: sum minK + loss.
// ---------------------------------------------------------------------------
__global__ __launch_bounds__(256) void vq_tail(
    const float* __restrict__ x, const float* __restrict__ cb,
    float* __restrict__ out, const unsigned* __restrict__ counter,
    const int* __restrict__ amb, float* __restrict__ gsumsq,
    unsigned* __restrict__ ticket, const unsigned* __restrict__ minK,
    float* __restrict__ out_loss)
{
    __shared__ __align__(16) float cbS[16384];   // 64 KB: 256 codes x 64 dims
    __shared__ double xs[64];
    __shared__ double bd[256];
    __shared__ int    bi[256];
    __shared__ unsigned lastS;
    __shared__ float redS[4];

    const int tid = threadIdx.x;

    // ---- A: fp64 re-decision for ambiguous rows (coalesced cb staging) ----
    unsigned cnt = *counter; if (cnt > AMB_CAP) cnt = AMB_CAP;
    for (unsigned i = blockIdx.x; i < cnt; i += gridDim.x) {
        int row = amb[2*i], oldk = amb[2*i+1];
        __syncthreads();
        if (tid < 64) xs[tid] = (double)x[(size_t)row*64 + tid];
        __syncthreads();
        double xn = 0.0;
        #pragma unroll 8
        for (int d = 0; d < 64; d++) xn += xs[d]*xs[d];
        double best = INFINITY; int bk = 1 << 30;
        for (int b = 0; b < 4; b++) {           // 256 codes per batch
            __syncthreads();                    // cbS free for reuse
            #pragma unroll
            for (int k = 0; k < 16; k++)        // 64 KB coalesced: 16 float4/thread
                ((float4*)cbS)[k*256 + tid] = ((const float4*)cb)[b*4096 + k*256 + tid];
            __syncthreads();
            int kcode = b*256 + tid;
            const int t6 = tid & 63;
            double dot = 0.0, cn2 = 0.0;
            #pragma unroll 8
            for (int dd = 0; dd < 64; dd++) {
                int d = (dd + t6) & 63;         // rotation: 2 lanes/bank (free)
                double cv = (double)cbS[tid*64 + d];
                dot = fma(xs[d], cv, dot);
                cn2 = fma(cv, cv, cn2);
            }
            double dist = (xn - 2.0*dot) + cn2;
            if (dist < best || (dist == best && kcode < bk)) { best = dist; bk = kcode; }
        }
        bd[tid] = best; bi[tid] = bk;
        __syncthreads();
        for (int s = 128; s > 0; s >>= 1) {
            if (tid < s) {
                double od = bd[tid+s]; int ok = bi[tid+s];
                if (od < bd[tid] || (od == bd[tid] && ok < bi[tid])) { bd[tid] = od; bi[tid] = ok; }
            }
            __syncthreads();
        }
        int bestk = bi[0];
        if (bestk != oldk) {
            double part = 0.0;
            if (tid < 64) {
                float cn = cb[(size_t)bestk*64 + tid];
                float co = cb[(size_t)oldk*64 + tid];
                out[(size_t)row*64 + tid] = cn;
                double dn = (double)cn - xs[tid];
                double dl = (double)co - xs[tid];
                part = dn*dn - dl*dl;
            }
            __syncthreads();
            bd[tid] = part;
            __syncthreads();
            for (int s = 128; s > 0; s >>= 1) {
                if (tid < s) bd[tid] += bd[tid+s];
                __syncthreads();
            }
            if (tid == 0) atomicAdd(gsumsq, (float)bd[0]);
        }
    }

    // ---- B: last block assembles the loss ----
    __syncthreads();
    if (tid == 0) {
        __threadfence();
        lastS = (atomicAdd(ticket, 1u) == 63u) ? 1u : 0u;
    }
    __syncthreads();
    if (lastS) {
        __threadfence();
        float s = 0.f;
        #pragma unroll
        for (int jj = 0; jj < 4; jj++)
            s += __uint_as_float(minK[jj*256 + tid]);   // raw bits of positive dists
        #pragma unroll
        for (int o = 32; o > 0; o >>= 1) s += __shfl_down(s, o);
        if ((tid & 63) == 0) redS[tid >> 6] = s;
        __syncthreads();
        if (tid == 0) {
            float gs = atomicAdd(gsumsq, 0.0f);         // coherent device-scope read
            float tot = redS[0] + redS[1] + redS[2] + redS[3];
            out_loss[0] = 1.25f * (gs / 2097152.0f) + 0.1f * (tot / 1024.0f);
        }
    }
}

extern "C" void kernel_launch(void* const* d_in, const int* in_sizes, int n_in,
                              void* d_out, int out_size, void* d_ws, size_t ws_size,
                              hipStream_t stream) {
    const float* x  = (const float*)d_in[0];   // [32768, 64]
    const float* cb = (const float*)d_in[1];   // [1024, 64]
    float* out = (float*)d_out;                // [0,2097152): emb; [2097152]: loss

    char* ws = (char*)d_ws;
    unsigned*       counter = (unsigned*)ws;                    // @0
    float*          gsumsq  = (float*)(ws + 4);                 // @4
    unsigned*       ticket  = (unsigned*)(ws + 8);              // @8
    float*          cn4     = (float*)(ws + 1024);              // 4 KB
    unsigned*       minK    = (unsigned*)(ws + 8192);           // 4 KB
    int*            amb     = (int*)(ws + 16384);               // 64 KB
    unsigned short* wsB     = (unsigned short*)(ws + 131072);   // 256 KB

    vq_prep<<<16,  64,  0, stream>>>(cb, cn4, minK, counter, gsumsq, ticket, wsB);
    vq_main<<<512, 512, 0, stream>>>(x, cb, wsB, cn4, out, minK, counter, amb, gsumsq);
    vq_tail<<<64,  256, 0, stream>>>(x, cb, out, counter, amb, gsumsq, ticket, minK,
                                     out + 2097152);
}